// Round 5
// baseline (283.794 us; speedup 1.0000x reference)
//
#include <hip/hip_runtime.h>

// MultiRegionalFusionModule: out[b,t,s,f] = tgt[b,t,s,f] +
//   sum_k softmax_k(corr[tci[b,t], ri[k]]) * rv[b,k,f,s]
// B=8 T=32 S=512 F=128 K=64 N=200, fp32.
//
// R7 == R6 with compile fix: __builtin_nontemporal_* requires a NATIVE
// clang vector type, not HIP_vector_type<float,4>. Use ext_vector_type(4).
//
// R6 theory (untested due to compile error): all slow kernels shared
// VGPR_Count 32-52 => serial load->wait->FMA, ~1 load in flight/wave ->
// ~2.5 TB/s effective under congestion. Fix: __launch_bounds__(1024,4)
// (128 VGPR cap) + explicit 8-deep rotating load buffer (static indices)
// => 8 loads in flight/wave. rv loads nontemporal (single-use stream,
// keep LLC for ctx); ctx stores cacheable -> phase-B ctx reads LLC-hit.

constexpr int Bn = 8, Tn = 32, Sn = 512, Fn = 128, Kn = 64, Nn = 200;

typedef float f32x4 __attribute__((ext_vector_type(4)));

#define FMA4(A, V, S)                                        \
    (A).x = fmaf((V).x, (S), (A).x);                         \
    (A).y = fmaf((V).y, (S), (A).y);                         \
    (A).z = fmaf((V).z, (S), (A).z);                         \
    (A).w = fmaf((V).w, (S), (A).w)

// ---------- Phase A: ctx[b,t,f,s] = sum_k attn[b,t,k] * rv[b,k,f,s] -------
// grid 512 = b(8) x fp(64); block 1024 = 16 waves.
// wave w: sh=w&1 (s half), fi=(w>>1)&1 (f within pair), tg=w>>2 (t chunk of 8)
// lane: s = sh*256 + lane*4  -> one global_load_dwordx4 per k = 1KB contig.
__global__ __launch_bounds__(1024, 4)
void mrf_ctx(const float* __restrict__ rv,
             const float* __restrict__ corr,
             const int*   __restrict__ tci,
             const int*   __restrict__ ri,
             float*       __restrict__ ctx)
{
    __shared__ float attnT[Kn][36];   // rows 144B: float4 reads 16B-aligned

    const int tid  = threadIdx.x;
    const int w    = tid >> 6;
    const int lane = tid & 63;
    const int bid  = blockIdx.x;
    const int b    = bid >> 6;
    const int fp   = bid & 63;

    // softmax over K (lane = k); 16 waves x 2 rounds cover t = 0..31
    {
        const int rik = ri[lane];
        #pragma unroll
        for (int j = 0; j < 2; ++j) {
            const int t   = w + 16 * j;
            const int row = tci[b * Tn + t];
            float c = corr[row * Nn + rik];
            float m = c;
            #pragma unroll
            for (int off = 32; off; off >>= 1)
                m = fmaxf(m, __shfl_xor(m, off));
            float e = __expf(c - m);
            float s = e;
            #pragma unroll
            for (int off = 32; off; off >>= 1)
                s += __shfl_xor(s, off);
            attnT[lane][t] = e / s;
        }
    }
    __syncthreads();

    const int sh = w & 1;
    const int fi = (w >> 1) & 1;
    const int tg = w >> 2;
    const int t0 = tg * 8;
    const int f  = fp * 2 + fi;

    const size_t FS = (size_t)Fn * Sn;     // k stride in floats (64K)
    const float* rvp = rv + ((size_t)(b * Kn) * Fn + f) * (size_t)Sn
                          + sh * 256 + lane * 4;

    f32x4 c0 = (f32x4)0.f, c1 = (f32x4)0.f, c2 = (f32x4)0.f, c3 = (f32x4)0.f,
          c4 = (f32x4)0.f, c5 = (f32x4)0.f, c6 = (f32x4)0.f, c7 = (f32x4)0.f;

    // 8-deep rotating load pipeline; all buf indices compile-time static.
    f32x4 buf[8];
    #pragma unroll
    for (int i = 0; i < 8; ++i)
        buf[i] = __builtin_nontemporal_load(
                     (const f32x4*)(rvp + (size_t)i * FS));

    for (int kb = 0; kb < Kn; kb += 8) {
        const bool pf = (kb + 8 < Kn);     // wave-uniform prefetch guard
        #pragma unroll
        for (int j = 0; j < 8; ++j) {
            const f32x4 v = buf[j];
            if (pf)
                buf[j] = __builtin_nontemporal_load(
                             (const f32x4*)(rvp + (size_t)(kb + 8 + j) * FS));
            const float4 a0 = *(const float4*)&attnT[kb + j][t0];     // bcast
            const float4 a1 = *(const float4*)&attnT[kb + j][t0 + 4]; // bcast
            FMA4(c0, v, a0.x); FMA4(c1, v, a0.y);
            FMA4(c2, v, a0.z); FMA4(c3, v, a0.w);
            FMA4(c4, v, a1.x); FMA4(c5, v, a1.y);
            FMA4(c6, v, a1.z); FMA4(c7, v, a1.w);
        }
    }

    // ctx stores: 1KB contiguous per (t, f-row) per wave; keep cacheable
    // (phase B re-reads ctx; 64 MiB fits LLC).
    float* cp = ctx + ((size_t)(b * Tn + t0) * Fn + f) * (size_t)Sn
                    + sh * 256 + lane * 4;
    const size_t ts = FS;                  // t stride in floats
    *(f32x4*)(cp + 0 * ts) = c0;
    *(f32x4*)(cp + 1 * ts) = c1;
    *(f32x4*)(cp + 2 * ts) = c2;
    *(f32x4*)(cp + 3 * ts) = c3;
    *(f32x4*)(cp + 4 * ts) = c4;
    *(f32x4*)(cp + 5 * ts) = c5;
    *(f32x4*)(cp + 6 * ts) = c6;
    *(f32x4*)(cp + 7 * ts) = c7;
}

// ---------- Phase B: out[b,t,s,f] = tgt[b,t,s,f] + ctx[b,t,f,s] -----------
// grid 4096 = b(8) x t(32) x sg(8) x fg(2); block 256. 64x64 LDS transpose.
__global__ __launch_bounds__(256, 8)
void mrf_tadd(const float* __restrict__ tgt,
              const float* __restrict__ ctx,
              float*       __restrict__ out)
{
    __shared__ float tile[64][65];

    const int tid = threadIdx.x;
    const int bid = blockIdx.x;
    const int fg  = bid & 1;
    const int sg  = (bid >> 1) & 7;
    const int t   = (bid >> 4) & 31;
    const int b   = bid >> 9;
    const int s0  = sg * 64;
    const int f0  = fg * 64;

    const int r0 = tid >> 4;          // 0..15
    const int x4 = (tid & 15) * 4;    // 0,4,..,60

    // read ctx[f-local][s-local]: LLC-hot from phase A; cacheable
    const size_t cbase = ((size_t)(b * Tn + t) * Fn + f0) * (size_t)Sn + s0;
    #pragma unroll
    for (int p = 0; p < 4; ++p) {
        const int r = p * 16 + r0;
        const float4 v = *(const float4*)(ctx + cbase + (size_t)r * Sn + x4);
        tile[r][x4 + 0] = v.x;
        tile[r][x4 + 1] = v.y;
        tile[r][x4 + 2] = v.z;
        tile[r][x4 + 3] = v.w;
    }
    __syncthreads();

    // write out[s-local][f-local] + tgt: single-touch -> nontemporal
    const size_t obase = ((size_t)(b * Tn + t) * Sn + s0) * (size_t)Fn + f0;
    #pragma unroll
    for (int p = 0; p < 4; ++p) {
        const int ss = p * 16 + r0;
        const size_t o = obase + (size_t)ss * Fn + x4;
        const f32x4 tv = __builtin_nontemporal_load(
                             (const f32x4*)(tgt + o));
        f32x4 ov;
        ov.x = tv.x + tile[x4 + 0][ss];
        ov.y = tv.y + tile[x4 + 1][ss];
        ov.z = tv.z + tile[x4 + 2][ss];
        ov.w = tv.w + tile[x4 + 3][ss];
        __builtin_nontemporal_store(ov, (f32x4*)(out + o));
    }
}

// ---------- Fallback (R4 single-kernel, harness-verified) ------------------
constexpr int S_TILE = 32;
constexpr int F_TILE = 8;

__global__ __launch_bounds__(256, 8)
void mrf_fallback(const float* __restrict__ tgt,
                  const float* __restrict__ rv,
                  const float* __restrict__ corr,
                  const int*   __restrict__ tci,
                  const int*   __restrict__ ri,
                  float*       __restrict__ out)
{
    __shared__ float attnT[Kn][36];
    __shared__ float etile[4][S_TILE][12];

    const int tid  = threadIdx.x;
    const int w    = tid >> 6;
    const int lane = tid & 63;

    const int bid = blockIdx.x;
    const int fb  = bid >> 7;
    const int r_  = bid & 127;
    const int b   = r_ >> 4;
    const int sb  = r_ & 15;
    const int s0  = sb * S_TILE;
    const int f0  = fb * F_TILE;

    {
        const int rik = ri[lane];
        #pragma unroll
        for (int j = 0; j < 8; ++j) {
            const int t   = w + 4 * j;
            const int row = tci[b * Tn + t];
            float c = corr[row * Nn + rik];
            float m = c;
            #pragma unroll
            for (int off = 32; off; off >>= 1)
                m = fmaxf(m, __shfl_xor(m, off));
            float e = __expf(c - m);
            float s = e;
            #pragma unroll
            for (int off = 32; off; off >>= 1)
                s += __shfl_xor(s, off);
            attnT[lane][t] = e / s;
        }
    }
    __syncthreads();

    const int t0 = w * 8;
    const int sq = lane & 7;
    const int fr = lane >> 3;

    float4 acc[8];
    #pragma unroll
    for (int tt = 0; tt < 8; ++tt) {
        acc[tt].x = 0.0f; acc[tt].y = 0.0f;
        acc[tt].z = 0.0f; acc[tt].w = 0.0f;
    }

    const float* rvp = rv + ((size_t)(b * Kn) * Fn + f0 + fr) * (size_t)Sn
                          + s0 + 4 * sq;

    #pragma unroll 2
    for (int k = 0; k < Kn; ++k) {
        const float4 v4 = *(const float4*)(rvp + (size_t)k * (Fn * Sn));
        const float4 a0 = *(const float4*)&attnT[k][t0];
        const float4 a1 = *(const float4*)&attnT[k][t0 + 4];
        FMA4(acc[0], v4, a0.x); FMA4(acc[1], v4, a0.y);
        FMA4(acc[2], v4, a0.z); FMA4(acc[3], v4, a0.w);
        FMA4(acc[4], v4, a1.x); FMA4(acc[5], v4, a1.y);
        FMA4(acc[6], v4, a1.z); FMA4(acc[7], v4, a1.w);
    }

    const int ss = lane >> 1;
    const int fh = lane & 1;
    float* et = &etile[w][0][0];

    #pragma unroll
    for (int tt = 0; tt < 8; ++tt) {
        et[(4 * sq + 0) * 12 + fr] = acc[tt].x;
        et[(4 * sq + 1) * 12 + fr] = acc[tt].y;
        et[(4 * sq + 2) * 12 + fr] = acc[tt].z;
        et[(4 * sq + 3) * 12 + fr] = acc[tt].w;
        const int t = t0 + tt;
        const size_t rb = (((size_t)(b * Tn + t)) * Sn + s0 + ss) * (size_t)Fn
                          + f0 + 4 * fh;
        const float4 tv = *(const float4*)(tgt + rb);
        const float4 cv = *(const float4*)&et[ss * 12 + 4 * fh];
        float4 o;
        o.x = tv.x + cv.x; o.y = tv.y + cv.y;
        o.z = tv.z + cv.z; o.w = tv.w + cv.w;
        *(float4*)(out + rb) = o;
    }
}

extern "C" void kernel_launch(void* const* d_in, const int* in_sizes, int n_in,
                              void* d_out, int out_size, void* d_ws, size_t ws_size,
                              hipStream_t stream)
{
    const float* tgt  = (const float*)d_in[0];   // [B,T,S,F]
    const float* rv   = (const float*)d_in[1];   // [B,K,F,S]
    const float* corr = (const float*)d_in[2];   // [N,N]
    const int*   tci  = (const int*)d_in[3];     // [B,T]
    const int*   ri   = (const int*)d_in[4];     // [K]
    float*       out  = (float*)d_out;           // [B,T,S,F]

    const size_t ctx_bytes = (size_t)Bn * Tn * Fn * Sn * sizeof(float); // 64 MiB
    if (ws_size >= ctx_bytes) {
        float* ctx = (float*)d_ws;               // [B,T,F,S]
        hipLaunchKernelGGL(mrf_ctx, dim3(Bn * (Fn / 2)), dim3(1024), 0, stream,
                           rv, corr, tci, ri, ctx);
        hipLaunchKernelGGL(mrf_tadd, dim3(Bn * Tn * (Sn / 64) * (Fn / 64)),
                           dim3(256), 0, stream, tgt, ctx, out);
    } else {
        hipLaunchKernelGGL(mrf_fallback, dim3(2048), dim3(256), 0, stream,
                           tgt, rv, corr, tci, ri, out);
    }
}